// Round 2
// baseline (1406.349 us; speedup 1.0000x reference)
//
#include <hip/hip_runtime.h>

constexpr int B_  = 8;
constexpr int N1_ = 8192;
constexpr int N2_ = 2048;
constexpr int K_  = 8;
constexpr int C1_ = 64;
constexpr int C2_ = 128;
constexpr int CIN0_ = C2_ + 3;   // 131
constexpr int M0_ = 128;
constexpr int M2IN_ = 192;       // 128 pooled + 64 feat1

// ---------------------------------------------------------------------------
// KNN: one thread per query point; xyz2 of this batch staged in LDS.
// Register-resident sorted top-8; strict < keeps the earlier index on exact
// ties (stable top-k semantics). FP contraction off so d2 rounding matches
// the np/XLA elementwise square + summed computation.
// ---------------------------------------------------------------------------
__global__ __launch_bounds__(256) void knn_kernel(const float* __restrict__ xyz1,
                                                  const float* __restrict__ xyz2,
                                                  int* __restrict__ idx) {
    __shared__ float s[N2_ * 3];
    const int b = blockIdx.y;
    const float* x2 = xyz2 + (size_t)b * N2_ * 3;
    for (int t = threadIdx.x; t < N2_ * 3; t += 256) s[t] = x2[t];
    __syncthreads();

    const int n = blockIdx.x * 256 + threadIdx.x;
    const float* q = xyz1 + ((size_t)b * N1_ + n) * 3;
    const float qx = q[0], qy = q[1], qz = q[2];

    float bd[K_];
    int   bi[K_];
#pragma unroll
    for (int t = 0; t < K_; ++t) { bd[t] = 3.0e38f; bi[t] = 0; }

    for (int j = 0; j < N2_; ++j) {
#pragma clang fp contract(off)
        const float dx = qx - s[3 * j + 0];
        const float dy = qy - s[3 * j + 1];
        const float dz = qz - s[3 * j + 2];
        const float dx2 = dx * dx;
        const float dy2 = dy * dy;
        const float dz2 = dz * dz;
        const float d2 = (dx2 + dy2) + dz2;
        if (d2 < bd[K_ - 1]) {
            bd[K_ - 1] = d2; bi[K_ - 1] = j;
#pragma unroll
            for (int t = K_ - 1; t >= 1; --t) {
                if (bd[t] < bd[t - 1]) {
                    float td = bd[t]; bd[t] = bd[t - 1]; bd[t - 1] = td;
                    int   ti = bi[t]; bi[t] = bi[t - 1]; bi[t - 1] = ti;
                }
            }
        }
    }

    const int base = (b * N1_ + n) * K_;
#pragma unroll
    for (int t = 0; t < K_; ++t) idx[base + t] = bi[t];
}

// ---------------------------------------------------------------------------
// Fused gather + MLP0 + MLP1 + maxpool + concat(feat1) + MLP2, one block
// (128 threads, thread = output channel) per (b, n) point. All intermediates
// stay in LDS/registers; only idx is read from ws and out written to HBM.
// ---------------------------------------------------------------------------
__global__ __launch_bounds__(128) void fused_kernel(
    const float* __restrict__ xyz1, const float* __restrict__ xyz2,
    const float* __restrict__ feat1, const float* __restrict__ feat2,
    const float* __restrict__ W0, const float* __restrict__ b0,
    const float* __restrict__ W1, const float* __restrict__ b1,
    const float* __restrict__ W2, const float* __restrict__ b2,
    const int* __restrict__ idx, float* __restrict__ out) {
    const int b = blockIdx.y;
    const int n = blockIdx.x;
    const int c = threadIdx.x;  // 0..127, output channel

    __shared__ float in_s[K_][132];   // 131 used, padded
    __shared__ float net1_s[K_][128];
    __shared__ float cat_s[M2IN_];    // [0..127]=pooled, [128..191]=feat1

    const int* id = idx + ((size_t)(b * N1_ + n)) * K_;
#pragma unroll
    for (int k = 0; k < K_; ++k) {
        const int j = id[k];
        in_s[k][c] = feat2[((size_t)b * N2_ + j) * C2_ + c];
        if (c < 3) {
            in_s[k][C2_ + c] = xyz2[((size_t)b * N2_ + j) * 3 + c] -
                               xyz1[((size_t)b * N1_ + n) * 3 + c];
        }
    }
    if (c < C1_) cat_s[128 + c] = feat1[((size_t)b * N1_ + n) * C1_ + c];
    __syncthreads();

    // Layer 0: 131 -> 128, relu
    float acc[K_];
    const float bias0 = b0[c];
#pragma unroll
    for (int k = 0; k < K_; ++k) acc[k] = bias0;
    for (int i = 0; i < CIN0_; ++i) {
        const float w = W0[i * 128 + c];
#pragma unroll
        for (int k = 0; k < K_; ++k) acc[k] += in_s[k][i] * w;
    }
#pragma unroll
    for (int k = 0; k < K_; ++k) net1_s[k][c] = fmaxf(acc[k], 0.0f);
    __syncthreads();

    // Layer 1: 128 -> 128, relu, then max-pool over K
    float acc2[K_];
    const float bias1 = b1[c];
#pragma unroll
    for (int k = 0; k < K_; ++k) acc2[k] = bias1;
    for (int i = 0; i < M0_; ++i) {
        const float w = W1[i * 128 + c];
#pragma unroll
        for (int k = 0; k < K_; ++k) acc2[k] += net1_s[k][i] * w;
    }
    float m = acc2[0];
#pragma unroll
    for (int k = 1; k < K_; ++k) m = fmaxf(m, acc2[k]);
    cat_s[c] = fmaxf(m, 0.0f);  // relu(max) == max(relu)
    __syncthreads();

    // Layer 2: 192 -> 128, relu
    float acc3 = b2[c];
    for (int i = 0; i < M2IN_; ++i) acc3 += cat_s[i] * W2[i * 128 + c];
    out[((size_t)(b * N1_) + n) * 128 + c] = fmaxf(acc3, 0.0f);
}

extern "C" void kernel_launch(void* const* d_in, const int* in_sizes, int n_in,
                              void* d_out, int out_size, void* d_ws, size_t ws_size,
                              hipStream_t stream) {
    const float* xyz1  = (const float*)d_in[0];
    const float* xyz2  = (const float*)d_in[1];
    const float* feat1 = (const float*)d_in[2];
    const float* feat2 = (const float*)d_in[3];
    const float* W0    = (const float*)d_in[4];
    const float* b0    = (const float*)d_in[5];
    const float* W1    = (const float*)d_in[6];
    const float* b1    = (const float*)d_in[7];
    const float* W2    = (const float*)d_in[8];
    const float* b2    = (const float*)d_in[9];
    float* out = (float*)d_out;

    int* idx = (int*)d_ws;  // B*N1*K int32 = 2 MB

    knn_kernel<<<dim3(N1_ / 256, B_), 256, 0, stream>>>(xyz1, xyz2, idx);
    fused_kernel<<<dim3(N1_, B_), 128, 0, stream>>>(xyz1, xyz2, feat1, feat2,
                                                    W0, b0, W1, b1, W2, b2,
                                                    idx, out);
}

// Round 3
// 527.741 us; speedup vs baseline: 2.6648x; 2.6648x over previous
//
#include <hip/hip_runtime.h>
#include <hip/hip_bf16.h>

constexpr int B_  = 8;
constexpr int N1_ = 8192;
constexpr int N2_ = 2048;
constexpr int K_  = 8;

typedef short bf16x8 __attribute__((ext_vector_type(8)));
typedef float f32x4  __attribute__((ext_vector_type(4)));

__device__ __forceinline__ short f2b(float x) {
    __hip_bfloat16 h = __float2bfloat16(x);  // RNE
    return *reinterpret_cast<short*>(&h);
}

// ---------------------------------------------------------------------------
// Prep 1: feat2 f32 -> bf16 (2M elems), 4 per thread.
// ---------------------------------------------------------------------------
__global__ __launch_bounds__(256) void prep_feat2(const float* __restrict__ feat2,
                                                  short* __restrict__ feat2b) {
    const int i = blockIdx.x * 256 + threadIdx.x;  // 524288 threads
    const float4 v = ((const float4*)feat2)[i];
    uint2 o;
    o.x = (unsigned short)f2b(v.x) | ((unsigned)(unsigned short)f2b(v.y) << 16);
    o.y = (unsigned short)f2b(v.z) | ((unsigned)(unsigned short)f2b(v.w) << 16);
    ((uint2*)feat2b)[i] = o;
}

// ---------------------------------------------------------------------------
// Prep 2: weights -> transposed bf16 [n][k] (k contiguous), W0 k-padded with
// zeros to 160; also pack xyz2 into float4 for scalar-load KNN.
// W0T: 128x160, W1T: 128x128, W2T: 128x192.
// ---------------------------------------------------------------------------
__global__ __launch_bounds__(256) void prep_weights(
    const float* __restrict__ W0, const float* __restrict__ W1,
    const float* __restrict__ W2, const float* __restrict__ xyz2,
    short* __restrict__ W0T, short* __restrict__ W1T, short* __restrict__ W2T,
    float4* __restrict__ xpack) {
    int i = blockIdx.x * 256 + threadIdx.x;  // 304*256 = 77824 threads
    if (i < 128 * 160) {
        const int n = i / 160, k = i % 160;
        W0T[i] = (k < 131) ? f2b(W0[k * 128 + n]) : (short)0;
        return;
    }
    i -= 128 * 160;
    if (i < 128 * 128) {
        const int n = i >> 7, k = i & 127;
        W1T[i] = f2b(W1[k * 128 + n]);
        return;
    }
    i -= 128 * 128;
    if (i < 128 * 192) {
        const int n = i / 192, k = i % 192;
        W2T[i] = f2b(W2[k * 128 + n]);
        return;
    }
    i -= 128 * 192;
    // 8*2048 xyz2 points
    xpack[i] = make_float4(xyz2[i * 3 + 0], xyz2[i * 3 + 1], xyz2[i * 3 + 2], 0.f);
}

// ---------------------------------------------------------------------------
// KNN v2: exact same per-point f32 arithmetic/ordering as the verified round-2
// kernel (contract off, strict-< stable insert), but xyz2 read via wave-
// uniform float4 index (scalar loads, no LDS) and unrolled x8 with an exact
// conservative batch guard.
// ---------------------------------------------------------------------------
__global__ __launch_bounds__(256) void knn2(const float* __restrict__ xyz1,
                                            const float4* __restrict__ xpack,
                                            int* __restrict__ idx) {
    const int b = blockIdx.y;
    const int n = blockIdx.x * 256 + threadIdx.x;
    const float* q = xyz1 + ((size_t)b * N1_ + n) * 3;
    const float qx = q[0], qy = q[1], qz = q[2];
    const float4* P = xpack + (size_t)b * N2_;

    float bd[K_];
    int   bi[K_];
#pragma unroll
    for (int t = 0; t < K_; ++t) { bd[t] = 3.0e38f; bi[t] = 0; }

    for (int j0 = 0; j0 < N2_; j0 += 8) {
        float d2[8];
#pragma unroll
        for (int u = 0; u < 8; ++u) {
#pragma clang fp contract(off)
            const float4 p = P[j0 + u];
            const float dx = qx - p.x;
            const float dy = qy - p.y;
            const float dz = qz - p.z;
            const float dx2 = dx * dx;
            const float dy2 = dy * dy;
            const float dz2 = dz * dz;
            d2[u] = (dx2 + dy2) + dz2;
        }
        float mn = d2[0];
#pragma unroll
        for (int u = 1; u < 8; ++u) mn = fminf(mn, d2[u]);
        if (mn < bd[K_ - 1]) {
#pragma unroll
            for (int u = 0; u < 8; ++u) {
                if (d2[u] < bd[K_ - 1]) {
                    bd[K_ - 1] = d2[u]; bi[K_ - 1] = j0 + u;
#pragma unroll
                    for (int t = K_ - 1; t >= 1; --t) {
                        if (bd[t] < bd[t - 1]) {
                            float td = bd[t]; bd[t] = bd[t - 1]; bd[t - 1] = td;
                            int   ti = bi[t]; bi[t] = bi[t - 1]; bi[t - 1] = ti;
                        }
                    }
                }
            }
        }
    }

    const int base = (b * N1_ + n) * K_;
#pragma unroll
    for (int t = 0; t < K_; ++t) idx[base + t] = bi[t];
}

// ---------------------------------------------------------------------------
// Fused MFMA MLP: block = 256 thr (4 waves) = 16 points = 128 GEMM rows.
//   L0: A0(128x160 LDS, stride 168) x W0T(global) -> A1(LDS, stride 136)
//   L1: A1 x W1T -> in-register relu + maxpool(shfl) -> sCat(16x192, stride 200)
//   L2: sCat x W2T -> out (f32)
// MFMA 16x16x32 bf16; C/D: col=lane&15, row=(lane>>4)*4+reg  [m89-verified]
//      A: A[m=lane&15][k=(lane>>4)*8+j]                      [m120-verified]
// ---------------------------------------------------------------------------
__global__ __launch_bounds__(256) void fused_mfma(
    const float* __restrict__ xyz1, const float* __restrict__ xyz2,
    const float* __restrict__ feat1,
    const float* __restrict__ b0, const float* __restrict__ b1,
    const float* __restrict__ b2,
    const short* __restrict__ feat2b, const short* __restrict__ W0T,
    const short* __restrict__ W1T, const short* __restrict__ W2T,
    const int* __restrict__ idx, float* __restrict__ out) {
    __shared__ __align__(16) short sA[128 * 168];  // A0; later overlaid by A1 (stride 136)
    __shared__ __align__(16) short sCat[16 * 200];

    const int b = blockIdx.y;
    const int n0 = blockIdx.x * 16;
    const int tid = threadIdx.x;

    // ---- stage A0: rows = p*8+kk; k0..127 = feat2b[j], k128..130 = xyz diff, pad 0 ----
    {
        const int row = tid >> 1, half = tid & 1;
        const int p = row >> 3, kk = row & 7;
        const int n = n0 + p;
        const int j = idx[((size_t)b * N1_ + n) * K_ + kk];
        const uint4* src = (const uint4*)(feat2b + ((size_t)(b * N2_ + j)) * 128 + half * 64);
        uint4* dst = (uint4*)(sA + row * 168 + half * 64);
#pragma unroll
        for (int t = 0; t < 8; ++t) dst[t] = src[t];
        uint4* pad = (uint4*)(sA + row * 168 + 128 + half * 16);
        if (half == 0) {
            const float dx = xyz2[((size_t)b * N2_ + j) * 3 + 0] - xyz1[((size_t)b * N1_ + n) * 3 + 0];
            const float dy = xyz2[((size_t)b * N2_ + j) * 3 + 1] - xyz1[((size_t)b * N1_ + n) * 3 + 1];
            const float dz = xyz2[((size_t)b * N2_ + j) * 3 + 2] - xyz1[((size_t)b * N1_ + n) * 3 + 2];
            uint4 v;
            v.x = (unsigned short)f2b(dx) | ((unsigned)(unsigned short)f2b(dy) << 16);
            v.y = (unsigned short)f2b(dz);
            v.z = 0; v.w = 0;
            pad[0] = v;
            pad[1] = make_uint4(0, 0, 0, 0);
        } else {
            pad[0] = make_uint4(0, 0, 0, 0);
            pad[1] = make_uint4(0, 0, 0, 0);
        }
    }
    // ---- stage feat1 -> sCat cols 128..191 ----
    {
#pragma unroll
        for (int u = 0; u < 4; ++u) {
            const int e = tid * 4 + u;  // 0..1023
            const int p = e >> 6, c = e & 63;
            sCat[p * 200 + 128 + c] = f2b(feat1[((size_t)b * N1_ + n0 + p) * 64 + c]);
        }
    }
    __syncthreads();

    const int wave = tid >> 6, lane = tid & 63;
    const int q = lane >> 4, l15 = lane & 15;
    const int mBase = (wave & 1) * 64, nBase = (wave >> 1) * 64;

    const f32x4 zero4 = {0.f, 0.f, 0.f, 0.f};

    // ---------------- Layer 0: K=160 (5 ksteps) ----------------
    f32x4 acc[4][4];
#pragma unroll
    for (int mt = 0; mt < 4; ++mt)
#pragma unroll
        for (int nt = 0; nt < 4; ++nt) acc[mt][nt] = zero4;

    for (int ks = 0; ks < 5; ++ks) {
        bf16x8 af[4], bf[4];
#pragma unroll
        for (int mt = 0; mt < 4; ++mt)
            af[mt] = *(const bf16x8*)(sA + (mBase + mt * 16 + l15) * 168 + ks * 32 + q * 8);
#pragma unroll
        for (int nt = 0; nt < 4; ++nt)
            bf[nt] = *(const bf16x8*)(W0T + (nBase + nt * 16 + l15) * 160 + ks * 32 + q * 8);
#pragma unroll
        for (int mt = 0; mt < 4; ++mt)
#pragma unroll
            for (int nt = 0; nt < 4; ++nt)
                acc[mt][nt] = __builtin_amdgcn_mfma_f32_16x16x32_bf16(af[mt], bf[nt], acc[mt][nt], 0, 0, 0);
    }

    // bias + relu -> A1 overlay (stride 136)
    float b0v[4];
#pragma unroll
    for (int nt = 0; nt < 4; ++nt) b0v[nt] = b0[nBase + nt * 16 + l15];
    __syncthreads();  // all L0 reads of sA done before overlay writes
#pragma unroll
    for (int mt = 0; mt < 4; ++mt)
#pragma unroll
        for (int nt = 0; nt < 4; ++nt)
#pragma unroll
            for (int r = 0; r < 4; ++r) {
                const int row = mBase + mt * 16 + q * 4 + r;
                const int col = nBase + nt * 16 + l15;
                sA[row * 136 + col] = f2b(fmaxf(acc[mt][nt][r] + b0v[nt], 0.f));
            }
    __syncthreads();

    // ---------------- Layer 1: K=128 (4 ksteps) ----------------
    f32x4 acc2[4][4];
#pragma unroll
    for (int mt = 0; mt < 4; ++mt)
#pragma unroll
        for (int nt = 0; nt < 4; ++nt) acc2[mt][nt] = zero4;

    for (int ks = 0; ks < 4; ++ks) {
        bf16x8 af[4], bf[4];
#pragma unroll
        for (int mt = 0; mt < 4; ++mt)
            af[mt] = *(const bf16x8*)(sA + (mBase + mt * 16 + l15) * 136 + ks * 32 + q * 8);
#pragma unroll
        for (int nt = 0; nt < 4; ++nt)
            bf[nt] = *(const bf16x8*)(W1T + (nBase + nt * 16 + l15) * 128 + ks * 32 + q * 8);
#pragma unroll
        for (int mt = 0; mt < 4; ++mt)
#pragma unroll
            for (int nt = 0; nt < 4; ++nt)
                acc2[mt][nt] = __builtin_amdgcn_mfma_f32_16x16x32_bf16(af[mt], bf[nt], acc2[mt][nt], 0, 0, 0);
    }

    // bias + relu + in-register maxpool over 8 neighbors -> sCat cols 0..127
    float b1v[4];
#pragma unroll
    for (int nt = 0; nt < 4; ++nt) b1v[nt] = b1[nBase + nt * 16 + l15];
#pragma unroll
    for (int mt = 0; mt < 4; ++mt)
#pragma unroll
        for (int nt = 0; nt < 4; ++nt) {
            float vm = fmaxf(acc2[mt][nt][0] + b1v[nt], 0.f);
#pragma unroll
            for (int r = 1; r < 4; ++r) vm = fmaxf(vm, acc2[mt][nt][r] + b1v[nt]);
            const float other = __shfl_xor(vm, 16);
            const float pool = fmaxf(vm, other);  // q0/q1 -> even pt, q2/q3 -> odd pt
            if ((q & 1) == 0) {
                const int pp = (mBase >> 3) + mt * 2 + (q >> 1);
                sCat[pp * 200 + nBase + nt * 16 + l15] = f2b(pool);
            }
        }
    __syncthreads();

    // ---------------- Layer 2: M=16 pts, K=192 (6 ksteps), wave owns 32 cols ----------------
    f32x4 acc3[2];
    acc3[0] = zero4; acc3[1] = zero4;
    const int nB2 = wave * 32;
    for (int ks = 0; ks < 6; ++ks) {
        const bf16x8 a2 = *(const bf16x8*)(sCat + l15 * 200 + ks * 32 + q * 8);
#pragma unroll
        for (int nt = 0; nt < 2; ++nt) {
            const bf16x8 b2f = *(const bf16x8*)(W2T + (nB2 + nt * 16 + l15) * 192 + ks * 32 + q * 8);
            acc3[nt] = __builtin_amdgcn_mfma_f32_16x16x32_bf16(a2, b2f, acc3[nt], 0, 0, 0);
        }
    }
    float b2v[2];
#pragma unroll
    for (int nt = 0; nt < 2; ++nt) b2v[nt] = b2[nB2 + nt * 16 + l15];
#pragma unroll
    for (int nt = 0; nt < 2; ++nt)
#pragma unroll
        for (int r = 0; r < 4; ++r) {
            const int p = q * 4 + r;
            const int col = nB2 + nt * 16 + l15;
            out[((size_t)(b * N1_ + n0 + p)) * 128 + col] = fmaxf(acc3[nt][r] + b2v[nt], 0.f);
        }
}

extern "C" void kernel_launch(void* const* d_in, const int* in_sizes, int n_in,
                              void* d_out, int out_size, void* d_ws, size_t ws_size,
                              hipStream_t stream) {
    const float* xyz1  = (const float*)d_in[0];
    const float* xyz2  = (const float*)d_in[1];
    const float* feat1 = (const float*)d_in[2];
    const float* feat2 = (const float*)d_in[3];
    const float* W0    = (const float*)d_in[4];
    const float* b0    = (const float*)d_in[5];
    const float* W1    = (const float*)d_in[6];
    const float* b1    = (const float*)d_in[7];
    const float* W2    = (const float*)d_in[8];
    const float* b2    = (const float*)d_in[9];
    float* out = (float*)d_out;

    char* ws = (char*)d_ws;
    int*    idx    = (int*)(ws + 0);            // 2 MB
    short*  feat2b = (short*)(ws + 2097152);    // 4 MB
    short*  W0T    = (short*)(ws + 6291456);    // 40960 B
    short*  W1T    = (short*)(ws + 6332416);    // 32768 B
    short*  W2T    = (short*)(ws + 6365184);    // 49152 B
    float4* xpack  = (float4*)(ws + 6414336);   // 256 KB -> ends ~6.4 MB

    prep_feat2<<<2048, 256, 0, stream>>>(feat2, feat2b);
    prep_weights<<<304, 256, 0, stream>>>(W0, W1, W2, xyz2, W0T, W1T, W2T, xpack);
    knn2<<<dim3(N1_ / 256, B_), 256, 0, stream>>>(xyz1, xpack, idx);
    fused_mfma<<<dim3(N1_ / 16, B_), 256, 0, stream>>>(xyz1, xyz2, feat1, b0, b1, b2,
                                                       feat2b, W0T, W1T, W2T, idx, out);
}

// Round 5
// 330.242 us; speedup vs baseline: 4.2585x; 1.5980x over previous
//
#include <hip/hip_runtime.h>
#include <hip/hip_bf16.h>

constexpr int B_  = 8;
constexpr int N1_ = 8192;
constexpr int N2_ = 2048;
constexpr int K_  = 8;

typedef short bf16x8 __attribute__((ext_vector_type(8)));
typedef float f32x4  __attribute__((ext_vector_type(4)));

__device__ __forceinline__ short f2b(float x) {
    __hip_bfloat16 h = __float2bfloat16(x);  // RNE
    return *reinterpret_cast<short*>(&h);
}

// ---------------------------------------------------------------------------
// Prep 1: feat2 f32 -> bf16 (2M elems), 4 per thread.
// ---------------------------------------------------------------------------
__global__ __launch_bounds__(256) void prep_feat2(const float* __restrict__ feat2,
                                                  short* __restrict__ feat2b) {
    const int i = blockIdx.x * 256 + threadIdx.x;  // 524288 threads
    const float4 v = ((const float4*)feat2)[i];
    uint2 o;
    o.x = (unsigned short)f2b(v.x) | ((unsigned)(unsigned short)f2b(v.y) << 16);
    o.y = (unsigned short)f2b(v.z) | ((unsigned)(unsigned short)f2b(v.w) << 16);
    ((uint2*)feat2b)[i] = o;
}

// ---------------------------------------------------------------------------
// Prep 2: weights -> transposed bf16 [n][k] (k contiguous), W0 k-padded with
// zeros to 160; also pack xyz2 into float4 for scalar-load KNN.
// ---------------------------------------------------------------------------
__global__ __launch_bounds__(256) void prep_weights(
    const float* __restrict__ W0, const float* __restrict__ W1,
    const float* __restrict__ W2, const float* __restrict__ xyz2,
    short* __restrict__ W0T, short* __restrict__ W1T, short* __restrict__ W2T,
    float4* __restrict__ xpack) {
    int i = blockIdx.x * 256 + threadIdx.x;  // 304*256 = 77824 threads
    if (i < 128 * 160) {
        const int n = i / 160, k = i % 160;
        W0T[i] = (k < 131) ? f2b(W0[k * 128 + n]) : (short)0;
        return;
    }
    i -= 128 * 160;
    if (i < 128 * 128) {
        const int n = i >> 7, k = i & 127;
        W1T[i] = f2b(W1[k * 128 + n]);
        return;
    }
    i -= 128 * 128;
    if (i < 128 * 192) {
        const int n = i / 192, k = i % 192;
        W2T[i] = f2b(W2[k * 128 + n]);
        return;
    }
    i -= 128 * 192;
    // 8*2048 xyz2 points
    xpack[i] = make_float4(xyz2[i * 3 + 0], xyz2[i * 3 + 1], xyz2[i * 3 + 2], 0.f);
}

// ---------------------------------------------------------------------------
// KNN v3 (segmented): block = 256 thr = 64 queries x 4 segments (wave = one
// 512-point segment of xyz2). Per-thread arithmetic and ordering identical to
// the verified kernel (contract off, strict-< stable insert). Segment top-8
// lists are (d, idx)-sorted over ascending disjoint index ranges, so the
// 4-way strict-< merge (s ascending) reproduces the global stable top-8
// bit-exactly.
// ---------------------------------------------------------------------------
__global__ __launch_bounds__(256) void knn_seg(const float* __restrict__ xyz1,
                                               const float4* __restrict__ xpack,
                                               int* __restrict__ idx) {
    __shared__ float sD[64][33];  // [query][seg*8+t], padded vs 32-bank aliasing
    __shared__ int   sI[64][33];

    const int b = blockIdx.y;
    const int lane = threadIdx.x & 63;   // query within block
    const int s = threadIdx.x >> 6;      // segment 0..3
    const int n = blockIdx.x * 64 + lane;

    const float* q = xyz1 + ((size_t)b * N1_ + n) * 3;
    const float qx = q[0], qy = q[1], qz = q[2];
    const float4* P = xpack + (size_t)b * N2_ + s * 512;

    float bd[K_];
    int   bi[K_];
#pragma unroll
    for (int t = 0; t < K_; ++t) { bd[t] = 3.0e38f; bi[t] = 0; }

    for (int j0 = 0; j0 < 512; j0 += 8) {
        float d2[8];
#pragma unroll
        for (int u = 0; u < 8; ++u) {
#pragma clang fp contract(off)
            const float4 p = P[j0 + u];
            const float dx = qx - p.x;
            const float dy = qy - p.y;
            const float dz = qz - p.z;
            const float dx2 = dx * dx;
            const float dy2 = dy * dy;
            const float dz2 = dz * dz;
            d2[u] = (dx2 + dy2) + dz2;
        }
        float mn = d2[0];
#pragma unroll
        for (int u = 1; u < 8; ++u) mn = fminf(mn, d2[u]);
        if (mn < bd[K_ - 1]) {
#pragma unroll
            for (int u = 0; u < 8; ++u) {
                if (d2[u] < bd[K_ - 1]) {
                    bd[K_ - 1] = d2[u]; bi[K_ - 1] = s * 512 + j0 + u;
#pragma unroll
                    for (int t = K_ - 1; t >= 1; --t) {
                        if (bd[t] < bd[t - 1]) {
                            float td = bd[t]; bd[t] = bd[t - 1]; bd[t - 1] = td;
                            int   ti = bi[t]; bi[t] = bi[t - 1]; bi[t - 1] = ti;
                        }
                    }
                }
            }
        }
    }

#pragma unroll
    for (int t = 0; t < K_; ++t) { sD[lane][s * 8 + t] = bd[t]; sI[lane][s * 8 + t] = bi[t]; }
    __syncthreads();

    if (threadIdx.x < 64) {
        const int qq = threadIdx.x;
        int h[4] = {0, 0, 0, 0};  // items consumed per segment list
        const int base = (b * N1_ + n) * K_;  // n == qq + blockIdx.x*64 here (lane==threadIdx.x)
#pragma unroll
        for (int t = 0; t < K_; ++t) {
            float best = 3.1e38f;
            int   bidx = 0, bs = 0;
#pragma unroll
            for (int ss = 0; ss < 4; ++ss) {
                if (h[ss] < 8) {
                    const float d = sD[qq][ss * 8 + h[ss]];
                    if (d < best) { best = d; bidx = sI[qq][ss * 8 + h[ss]]; bs = ss; }
                }
            }
            h[bs]++;
            idx[base + t] = bidx;
        }
    }
}

// ---------------------------------------------------------------------------
// Fused MFMA MLP: block = 256 thr (4 waves) = 16 points = 128 GEMM rows.
//   L0: A0(128x160 LDS, stride 168) x W0T(global) -> A1(LDS, stride 136)
//   L1: A1 x W1T -> in-register relu + maxpool(shfl) -> sCat(16x192, stride 200)
//   L2: sCat x W2T -> out (f32)
// MFMA 16x16x32 bf16; C/D: col=lane&15, row=(lane>>4)*4+reg  [m89-verified]
// ---------------------------------------------------------------------------
__global__ __launch_bounds__(256) void fused_mfma(
    const float* __restrict__ xyz1, const float* __restrict__ xyz2,
    const float* __restrict__ feat1,
    const float* __restrict__ b0, const float* __restrict__ b1,
    const float* __restrict__ b2,
    const short* __restrict__ feat2b, const short* __restrict__ W0T,
    const short* __restrict__ W1T, const short* __restrict__ W2T,
    const int* __restrict__ idx, float* __restrict__ out) {
    __shared__ __align__(16) short sA[128 * 168];  // A0; later overlaid by A1 (stride 136)
    __shared__ __align__(16) short sCat[16 * 200];

    const int b = blockIdx.y;
    const int n0 = blockIdx.x * 16;
    const int tid = threadIdx.x;

    // ---- stage A0: rows = p*8+kk; k0..127 = feat2b[j], k128..130 = xyz diff, pad 0 ----
    {
        const int row = tid >> 1, half = tid & 1;
        const int p = row >> 3, kk = row & 7;
        const int n = n0 + p;
        const int j = idx[((size_t)b * N1_ + n) * K_ + kk];
        const uint4* src = (const uint4*)(feat2b + ((size_t)(b * N2_ + j)) * 128 + half * 64);
        uint4* dst = (uint4*)(sA + row * 168 + half * 64);
#pragma unroll
        for (int t = 0; t < 8; ++t) dst[t] = src[t];
        uint4* pad = (uint4*)(sA + row * 168 + 128 + half * 16);
        if (half == 0) {
            const float dx = xyz2[((size_t)b * N2_ + j) * 3 + 0] - xyz1[((size_t)b * N1_ + n) * 3 + 0];
            const float dy = xyz2[((size_t)b * N2_ + j) * 3 + 1] - xyz1[((size_t)b * N1_ + n) * 3 + 1];
            const float dz = xyz2[((size_t)b * N2_ + j) * 3 + 2] - xyz1[((size_t)b * N1_ + n) * 3 + 2];
            uint4 v;
            v.x = (unsigned short)f2b(dx) | ((unsigned)(unsigned short)f2b(dy) << 16);
            v.y = (unsigned short)f2b(dz);
            v.z = 0; v.w = 0;
            pad[0] = v;
            pad[1] = make_uint4(0, 0, 0, 0);
        } else {
            pad[0] = make_uint4(0, 0, 0, 0);
            pad[1] = make_uint4(0, 0, 0, 0);
        }
    }
    // ---- stage feat1 -> sCat cols 128..191 ----
    {
#pragma unroll
        for (int u = 0; u < 4; ++u) {
            const int e = tid * 4 + u;  // 0..1023
            const int p = e >> 6, c = e & 63;
            sCat[p * 200 + 128 + c] = f2b(feat1[((size_t)b * N1_ + n0 + p) * 64 + c]);
        }
    }
    __syncthreads();

    const int wave = tid >> 6, lane = tid & 63;
    const int q = lane >> 4, l15 = lane & 15;
    const int mBase = (wave & 1) * 64, nBase = (wave >> 1) * 64;

    const f32x4 zero4 = {0.f, 0.f, 0.f, 0.f};

    // ---------------- Layer 0: K=160 (5 ksteps) ----------------
    f32x4 acc[4][4];
#pragma unroll
    for (int mt = 0; mt < 4; ++mt)
#pragma unroll
        for (int nt = 0; nt < 4; ++nt) acc[mt][nt] = zero4;

    for (int ks = 0; ks < 5; ++ks) {
        bf16x8 af[4], bf[4];
#pragma unroll
        for (int mt = 0; mt < 4; ++mt)
            af[mt] = *(const bf16x8*)(sA + (mBase + mt * 16 + l15) * 168 + ks * 32 + q * 8);
#pragma unroll
        for (int nt = 0; nt < 4; ++nt)
            bf[nt] = *(const bf16x8*)(W0T + (nBase + nt * 16 + l15) * 160 + ks * 32 + q * 8);
#pragma unroll
        for (int mt = 0; mt < 4; ++mt)
#pragma unroll
            for (int nt = 0; nt < 4; ++nt)
                acc[mt][nt] = __builtin_amdgcn_mfma_f32_16x16x32_bf16(af[mt], bf[nt], acc[mt][nt], 0, 0, 0);
    }

    // bias + relu -> A1 overlay (stride 136)
    float b0v[4];
#pragma unroll
    for (int nt = 0; nt < 4; ++nt) b0v[nt] = b0[nBase + nt * 16 + l15];
    __syncthreads();  // all L0 reads of sA done before overlay writes
#pragma unroll
    for (int mt = 0; mt < 4; ++mt)
#pragma unroll
        for (int nt = 0; nt < 4; ++nt)
#pragma unroll
            for (int r = 0; r < 4; ++r) {
                const int row = mBase + mt * 16 + q * 4 + r;
                const int col = nBase + nt * 16 + l15;
                sA[row * 136 + col] = f2b(fmaxf(acc[mt][nt][r] + b0v[nt], 0.f));
            }
    __syncthreads();

    // ---------------- Layer 1: K=128 (4 ksteps) ----------------
    f32x4 acc2[4][4];
#pragma unroll
    for (int mt = 0; mt < 4; ++mt)
#pragma unroll
        for (int nt = 0; nt < 4; ++nt) acc2[mt][nt] = zero4;

    for (int ks = 0; ks < 4; ++ks) {
        bf16x8 af[4], bf[4];
#pragma unroll
        for (int mt = 0; mt < 4; ++mt)
            af[mt] = *(const bf16x8*)(sA + (mBase + mt * 16 + l15) * 136 + ks * 32 + q * 8);
#pragma unroll
        for (int nt = 0; nt < 4; ++nt)
            bf[nt] = *(const bf16x8*)(W1T + (nBase + nt * 16 + l15) * 128 + ks * 32 + q * 8);
#pragma unroll
        for (int mt = 0; mt < 4; ++mt)
#pragma unroll
            for (int nt = 0; nt < 4; ++nt)
                acc2[mt][nt] = __builtin_amdgcn_mfma_f32_16x16x32_bf16(af[mt], bf[nt], acc2[mt][nt], 0, 0, 0);
    }

    // bias + relu + in-register maxpool over 8 neighbors -> sCat cols 0..127
    float b1v[4];
#pragma unroll
    for (int nt = 0; nt < 4; ++nt) b1v[nt] = b1[nBase + nt * 16 + l15];
#pragma unroll
    for (int mt = 0; mt < 4; ++mt)
#pragma unroll
        for (int nt = 0; nt < 4; ++nt) {
            float vm = fmaxf(acc2[mt][nt][0] + b1v[nt], 0.f);
#pragma unroll
            for (int r = 1; r < 4; ++r) vm = fmaxf(vm, acc2[mt][nt][r] + b1v[nt]);
            const float other = __shfl_xor(vm, 16);
            const float pool = fmaxf(vm, other);  // q0/q1 -> even pt, q2/q3 -> odd pt
            if ((q & 1) == 0) {
                const int pp = (mBase >> 3) + mt * 2 + (q >> 1);
                sCat[pp * 200 + nBase + nt * 16 + l15] = f2b(pool);
            }
        }
    __syncthreads();

    // ---------------- Layer 2: M=16 pts, K=192 (6 ksteps), wave owns 32 cols ----------------
    f32x4 acc3[2];
    acc3[0] = zero4; acc3[1] = zero4;
    const int nB2 = wave * 32;
    for (int ks = 0; ks < 6; ++ks) {
        const bf16x8 a2 = *(const bf16x8*)(sCat + l15 * 200 + ks * 32 + q * 8);
#pragma unroll
        for (int nt = 0; nt < 2; ++nt) {
            const bf16x8 b2f = *(const bf16x8*)(W2T + (nB2 + nt * 16 + l15) * 192 + ks * 32 + q * 8);
            acc3[nt] = __builtin_amdgcn_mfma_f32_16x16x32_bf16(a2, b2f, acc3[nt], 0, 0, 0);
        }
    }
    float b2v[2];
#pragma unroll
    for (int nt = 0; nt < 2; ++nt) b2v[nt] = b2[nB2 + nt * 16 + l15];
#pragma unroll
    for (int nt = 0; nt < 2; ++nt)
#pragma unroll
        for (int r = 0; r < 4; ++r) {
            const int p = q * 4 + r;
            const int col = nB2 + nt * 16 + l15;
            out[((size_t)(b * N1_ + n0 + p)) * 128 + col] = fmaxf(acc3[nt][r] + b2v[nt], 0.f);
        }
}

extern "C" void kernel_launch(void* const* d_in, const int* in_sizes, int n_in,
                              void* d_out, int out_size, void* d_ws, size_t ws_size,
                              hipStream_t stream) {
    const float* xyz1  = (const float*)d_in[0];
    const float* xyz2  = (const float*)d_in[1];
    const float* feat1 = (const float*)d_in[2];
    const float* feat2 = (const float*)d_in[3];
    const float* W0    = (const float*)d_in[4];
    const float* b0    = (const float*)d_in[5];
    const float* W1    = (const float*)d_in[6];
    const float* b1    = (const float*)d_in[7];
    const float* W2    = (const float*)d_in[8];
    const float* b2    = (const float*)d_in[9];
    float* out = (float*)d_out;

    char* ws = (char*)d_ws;
    int*    idx    = (int*)(ws + 0);            // 2 MB
    short*  feat2b = (short*)(ws + 2097152);    // 4 MB
    short*  W0T    = (short*)(ws + 6291456);    // 40960 B
    short*  W1T    = (short*)(ws + 6332416);    // 32768 B
    short*  W2T    = (short*)(ws + 6365184);    // 49152 B
    float4* xpack  = (float4*)(ws + 6414336);   // 256 KB

    prep_feat2<<<2048, 256, 0, stream>>>(feat2, feat2b);
    prep_weights<<<304, 256, 0, stream>>>(W0, W1, W2, xyz2, W0T, W1T, W2T, xpack);
    knn_seg<<<dim3(N1_ / 64, B_), 256, 0, stream>>>(xyz1, xpack, idx);
    fused_mfma<<<dim3(N1_ / 16, B_), 256, 0, stream>>>(xyz1, xyz2, feat1, b0, b1, b2,
                                                       feat2b, W0T, W1T, W2T, idx, out);
}